// Round 9
// baseline (179.859 us; speedup 1.0000x reference)
//
#include <hip/hip_runtime.h>

#define BATCH 4096
#define N 64

// One DPP unsigned-max step: x = max(x, dpp_move(x)). VALU only.
template<int CTRL>
__device__ __forceinline__ unsigned dpp_umax(unsigned x) {
    unsigned moved = (unsigned)__builtin_amdgcn_update_dpp(0, (int)x, CTRL, 0xf, 0xf, true);
    return (moved > x) ? moved : x;
}

// Broadcast float from wave-uniform lane ps via v_readlane (SGPR result).
__device__ __forceinline__ float lanebcastf(float v, int ps) {
    return __uint_as_float(__builtin_amdgcn_readlane(__float_as_uint(v), ps));
}

// Packed-key argmax over live lanes: key = (bits(|col|) & ~63) | lane is
// monotone in |col| for floats >= 0 -> one umax tree + one readlane yields
// max AND pivot lane. Returns wave-uniform pivot lane.
__device__ __forceinline__ int pivot_argmax(float col, bool alive, int lane) {
    unsigned t = (__float_as_uint(col) & 0x7FFFFFC0u) | (unsigned)lane;
    unsigned r = alive ? t : 0u;
    r = dpp_umax<0x111>(r);   // row_shr:1
    r = dpp_umax<0x112>(r);   // row_shr:2
    r = dpp_umax<0x114>(r);   // row_shr:4
    r = dpp_umax<0x118>(r);   // row_shr:8
    r = dpp_umax<0x142>(r);   // row_bcast:15
    r = dpp_umax<0x143>(r);   // row_bcast:31
    return (int)(((unsigned)__builtin_amdgcn_readlane((int)r, 63)) & 63u);
}

// ONE WAVE PER DETERMINANT (round 9): block=128 = 2 waves; wave 0 does the
// up-det, wave 1 the dn-det of the same sample; 16B LDS combine. Total VALU
// work unchanged vs round 8, per-wave serial path halved, resident waves
// doubled. Probes the wave-serial-latency theory (rounds 3-8: time invariant
// to VGPR count / occupancy / structure; only chain-shortening moved it).
__global__ __launch_bounds__(128) void restricted_det_kernel(
    const float* __restrict__ U,
    const int* __restrict__ idx_up,
    const int* __restrict__ idx_dn,
    float* __restrict__ out)
{
    const int lane = threadIdx.x & 63;
    const int wv   = threadIdx.x >> 6;   // 0 = up, 1 = dn
    const int wid  = blockIdx.x;         // sample id

    const int* __restrict__ idx = wv ? idx_dn : idx_up;
    const int site = idx[wid * N + lane];

    // lane i holds row i of the gathered matrix, in registers
    float a[N];
    {
        const float4* __restrict__ row = reinterpret_cast<const float4*>(U + (long)site * N);
        #pragma unroll
        for (int q = 0; q < N / 4; ++q) {
            float4 v = row[q];
            a[4*q+0]=v.x; a[4*q+1]=v.y; a[4*q+2]=v.z; a[4*q+3]=v.w;
        }
    }

    float l2sum = 0.0f;                // sum log2|pivot| for this det
    unsigned sbits = 0u;               // xor of pivot sign bits (uniform)
    int inv = 0;                       // inversion count (uniform)
    unsigned long long chosen = 0ull;
    bool alive = true;

    // prologue: pivot for k=0
    int ps = pivot_argmax(a[0], alive, lane);

    #pragma unroll
    for (int k = 0; k < N - 1; ++k) {
        // ---- bookkeeping for step k (SALU, off-chain) ----
        inv += __popcll(chosen >> ps);
        chosen |= (1ull << ps);
        alive = alive && (lane != ps);

        const float pv = lanebcastf(a[k], ps);
        sbits ^= __float_as_uint(pv) & 0x80000000u;
        l2sum += __log2f(__builtin_fabsf(pv));

        // dead/pivot lanes free-run on garbage; safe: each pivot-row elem is
        // readlane'd before its owner's fma overwrites it, and dead rows are
        // never selected again.
        const float m = a[k] * __builtin_amdgcn_rcpf(pv);

        // ---- lookahead: update col k+1 only, then start its argmax ----
        {
            const float uv = lanebcastf(a[k + 1], ps);
            a[k + 1] = __builtin_fmaf(-m, uv, a[k + 1]);
        }
        const int ps_next = pivot_argmax(a[k + 1], alive, lane);

        // ---- bulk trailing update: cols k+2..63 (hides the chain) ----
        #pragma unroll
        for (int j = k + 2; j < N; ++j) {
            const float uv = lanebcastf(a[j], ps);
            a[j] = __builtin_fmaf(-m, uv, a[j]);
        }

        ps = ps_next;
    }

    // epilogue: last pivot (k = 63)
    inv += __popcll(chosen >> ps);
    chosen |= (1ull << ps);
    {
        const float pv = lanebcastf(a[N - 1], ps);
        sbits ^= __float_as_uint(pv) & 0x80000000u;
        l2sum += __log2f(__builtin_fabsf(pv));
    }

    // ---- combine the two dets of this sample via LDS ----
    __shared__ float sh_sgn[2];
    __shared__ float sh_l2[2];
    if (lane == 0) {
        sh_sgn[wv] = (((sbits >> 31) ^ ((unsigned)inv & 1u)) != 0u) ? -1.0f : 1.0f;
        sh_l2[wv]  = l2sum;
    }
    __syncthreads();
    if (threadIdx.x == 0) {
        out[wid] = sh_sgn[0] * sh_sgn[1];                              // sign product
        out[BATCH + wid] = (sh_l2[0] + sh_l2[1]) * 0.69314718055994530942f;  // ln
    }
}

extern "C" void kernel_launch(void* const* d_in, const int* in_sizes, int n_in,
                              void* d_out, int out_size, void* d_ws, size_t ws_size,
                              hipStream_t stream) {
    const float* U      = (const float*)d_in[0];
    const int*   idx_up = (const int*)d_in[1];
    const int*   idx_dn = (const int*)d_in[2];
    float* out = (float*)d_out;

    dim3 block(128);                 // 2 waves per block: up-det & dn-det
    dim3 grid(BATCH);                // one block per sample
    hipLaunchKernelGGL(restricted_det_kernel, grid, block, 0, stream,
                       U, idx_up, idx_dn, out);
}

// Round 12
// 166.960 us; speedup vs baseline: 1.0773x; 1.0773x over previous
//
#include <hip/hip_runtime.h>

#define BATCH 4096
#define N 64

// One DPP unsigned-max step: x = max(x, dpp_move(x)). VALU only.
template<int CTRL>
__device__ __forceinline__ unsigned dpp_umax(unsigned x) {
    unsigned moved = (unsigned)__builtin_amdgcn_update_dpp(0, (int)x, CTRL, 0xf, 0xf, true);
    return (moved > x) ? moved : x;
}

// Broadcast float from wave-uniform lane ps via v_readlane (SGPR result).
__device__ __forceinline__ float lanebcastf(float v, int ps) {
    return __uint_as_float(__builtin_amdgcn_readlane(__float_as_uint(v), ps));
}

// Packed-key argmax over live lanes: key = (bits(|col|) & ~63) | lane is
// monotone in |col| for floats >= 0 -> one umax tree + one readlane yields
// max AND pivot lane (wave-uniform).
__device__ __forceinline__ int pivot_argmax(float col, bool alive, int lane) {
    unsigned t = (__float_as_uint(col) & 0x7FFFFFC0u) | (unsigned)lane;
    unsigned r = alive ? t : 0u;
    r = dpp_umax<0x111>(r);   // row_shr:1
    r = dpp_umax<0x112>(r);   // row_shr:2
    r = dpp_umax<0x114>(r);   // row_shr:4
    r = dpp_umax<0x118>(r);   // row_shr:8
    r = dpp_umax<0x142>(r);   // row_bcast:15
    r = dpp_umax<0x143>(r);   // row_bcast:31
    return (int)(((unsigned)__builtin_amdgcn_readlane((int)r, 63)) & 63u);
}

// One elimination step with SHIFT-RENAMING: current pivot column is src[0];
// result written shifted (dst[j-1] = src[j] - m*u_j) so the next pivot
// column is dst[0]. All register indices compile-time; the k-loop can ROLL.
// W = max source column index updated this step (block-start width).
// Updates past the live range hit garbage columns that are never read.
template<int W>
__device__ __forceinline__ void lu_step(float (&src)[N], float (&dst)[N],
                                        int &ps, bool &alive,
                                        unsigned long long &chosen, int &inv,
                                        unsigned &sbits, float &l2sum,
                                        int lane)
{
    // bookkeeping for the current pivot (column src[0], lane ps)
    inv += __popcll(chosen >> ps);
    chosen |= (1ull << ps);
    alive = alive && (lane != ps);

    const float pv = lanebcastf(src[0], ps);
    sbits ^= __float_as_uint(pv) & 0x80000000u;
    l2sum += __log2f(__builtin_fabsf(pv));

    // dead/pivot lanes free-run on garbage; safe: each pivot-row elem is
    // readlane'd before its owner's fma overwrites it, and dead rows are
    // never selected again.
    const float m = src[0] * __builtin_amdgcn_rcpf(pv);

    // lookahead: produce next pivot column dst[0] first, start its argmax
    {
        const float uv = lanebcastf(src[1], ps);
        dst[0] = __builtin_fmaf(-m, uv, src[1]);
    }
    const int ps_next = pivot_argmax(dst[0], alive, lane);

    // bulk trailing update (independent stream hides the argmax chain)
    #pragma unroll
    for (int j = 2; j <= W; ++j) {
        const float uv = lanebcastf(src[j], ps);
        dst[j - 1] = __builtin_fmaf(-m, uv, src[j]);
    }
    ps = ps_next;
}

// 16 steps at fixed compile-time width W, ROLLED (8 ping-pong pairs).
// Static code ~2 step-bodies instead of 16.
template<int W>
__device__ __forceinline__ void lu_block16(float (&a)[N], float (&b)[N],
                                           int &ps, bool &alive,
                                           unsigned long long &chosen, int &inv,
                                           unsigned &sbits, float &l2sum,
                                           int lane)
{
    #pragma unroll 1
    for (int t = 0; t < 8; ++t) {
        lu_step<W>(a, b, ps, alive, chosen, inv, sbits, l2sum, lane);
        lu_step<W>(b, a, ps, alive, chosen, inv, sbits, l2sum, lane);
    }
}

// I-CACHE-RESIDENT LU (round 10/11/12): rounds 2-9 showed time is invariant
// to VGPR count / occupancy / per-wave latency, anti-correlates with resident
// waves (r9) and body size (r7): instruction-fetch bound, body ~40KB > 32KB
// L1I. This version rolls the k-loop via shift-renaming: ~6.5KB static.
__global__ __launch_bounds__(64) void restricted_det_kernel(
    const float* __restrict__ U,
    const int* __restrict__ idx_up,
    const int* __restrict__ idx_dn,
    float* __restrict__ out)
{
    const int lane = threadIdx.x;      // 0..63, one wave per block
    const int wid  = blockIdx.x;       // sample id

    const int site0 = idx_up[wid * N + lane];
    const int site1 = idx_dn[wid * N + lane];

    float l2sum = 0.0f;                // sum log2|pivot| over both dets
    unsigned sbits = 0u;               // xor of pivot sign bits (uniform)
    int inv = 0;                       // inversion count (uniform)

    #pragma unroll 1
    for (int spin = 0; spin < 2; ++spin) {
        const int site = (spin == 0) ? site0 : site1;

        // lane i holds row i of the gathered matrix, in registers
        float a[N], b[N];
        {
            const float4* __restrict__ row =
                reinterpret_cast<const float4*>(U + (long)site * N);
            #pragma unroll
            for (int q = 0; q < N / 4; ++q) {
                float4 v = row[q];
                a[4*q+0]=v.x; a[4*q+1]=v.y; a[4*q+2]=v.z; a[4*q+3]=v.w;
            }
        }

        unsigned long long chosen = 0ull;
        bool alive = true;

        // prologue: pivot for step 0
        int ps = pivot_argmax(a[0], alive, lane);

        // 64 steps = 4 rolled blocks of 16, widths shrink 63/47/31/15
        lu_block16<63>(a, b, ps, alive, chosen, inv, sbits, l2sum, lane);
        lu_block16<47>(a, b, ps, alive, chosen, inv, sbits, l2sum, lane);
        lu_block16<31>(a, b, ps, alive, chosen, inv, sbits, l2sum, lane);
        lu_block16<15>(a, b, ps, alive, chosen, inv, sbits, l2sum, lane);
    }

    if (lane == 0) {
        const float sgn =
            (((sbits >> 31) ^ ((unsigned)inv & 1u)) != 0u) ? -1.0f : 1.0f;
        out[wid] = sgn;                                        // sign_up * sign_dn
        out[BATCH + wid] = l2sum * 0.69314718055994530942f;    // ln from log2
    }
}

extern "C" void kernel_launch(void* const* d_in, const int* in_sizes, int n_in,
                              void* d_out, int out_size, void* d_ws, size_t ws_size,
                              hipStream_t stream) {
    const float* U      = (const float*)d_in[0];
    const int*   idx_up = (const int*)d_in[1];
    const int*   idx_dn = (const int*)d_in[2];
    float* out = (float*)d_out;

    dim3 block(64);                  // one wave per block, 1 sample per wave
    dim3 grid(BATCH);                // 4096 waves, exact cover
    hipLaunchKernelGGL(restricted_det_kernel, grid, block, 0, stream,
                       U, idx_up, idx_dn, out);
}